// Round 4
// baseline (18924.791 us; speedup 1.0000x reference)
//
#include <hip/hip_runtime.h>

#define BB    128
#define SEQL  336
#define PREDN 24
#define IN    64
#define HH    256
#define GG    1024          // 4*H
#define KTOT  320           // IN + H
#define NBLK  16            // 2 dirs x 8 btiles; block = (dir, btile), 1024 thr

typedef unsigned int   uint_t;
typedef unsigned short ush;
using s8v = __attribute__((ext_vector_type(8))) short;   // 8 bf16 (4 VGPRs)
using f4v = __attribute__((ext_vector_type(4))) float;   // MFMA acc

// ---- static device scratch (.bss; re-initialized by prep every call) ----
__device__ ush   g_webh[2 * 4 * 256 * KTOT];  // enc W bf16-hi [dir][gate][n][k]
__device__ ush   g_webl[2 * 4 * 256 * KTOT];  // enc W bf16-lo
__device__ ush   g_wdbh[2 * 4 * 256 * KTOT];  // dec W bf16-hi
__device__ ush   g_wdbl[2 * 4 * 256 * KTOT];  // dec W bf16-lo
__device__ ush   g_lwbh[64 * 512];            // linW bf16-hi  [o][k]
__device__ ush   g_lwbl[64 * 512];            // linW bf16-lo
__device__ float g_bs_enc[2 * GG];
__device__ float g_bs_dec[2 * GG];
__device__ float g_linb[IN];
__device__ float g_hx[PREDN * 2 * 8 * 4096];  // head h exchange, once-written per t
__device__ float g_yhist[2 * 8 * PREDN * 1024]; // block-private y history (f32)
__device__ int   g_xflag[16];                 // per-(dir,btile) monotonic flag

#define N_WT   (2 * 4 * 256 * KTOT)           // 655360
#define N_LW   (64 * 512)                     // 32768
#define N_PREP (2 * N_WT + N_LW + 4 * GG + IN + 16)

__device__ __forceinline__ void bfsplit(float v, uint_t& hi, uint_t& lo) {
    uint_t u = __float_as_uint(v);
    uint_t h = (u + 0x7FFFu + ((u >> 16) & 1u)) >> 16;          // RTN-even bf16
    float  r = v - __uint_as_float(h << 16);
    uint_t u2 = __float_as_uint(r);
    uint_t l = (u2 + 0x7FFFu + ((u2 >> 16) & 1u)) >> 16;
    hi = h; lo = l;
}

// Weights -> bf16 hi/lo [dir][gate][n][k]; linW -> [o][k] hi/lo; biases; flags.
__global__ void prep_kernel(const float* __restrict__ eWih,
                            const float* __restrict__ eWhh,
                            const float* __restrict__ ebih,
                            const float* __restrict__ ebhh,
                            const float* __restrict__ dWih,
                            const float* __restrict__ dWhh,
                            const float* __restrict__ dbih,
                            const float* __restrict__ dbhh,
                            const float* __restrict__ linW,
                            const float* __restrict__ linb)
{
    int idx = blockIdx.x * 256 + threadIdx.x;
    if (idx >= N_PREP) return;

    if (idx < N_WT) {                 // enc
        int d   = idx / (4 * 256 * KTOT);
        int sub = idx % (4 * 256 * KTOT);
        int g   = sub / (256 * KTOT);
        int n2  = (sub / KTOT) % 256;
        int k   = sub % KTOT;
        int j   = g * HH + n2;
        float v = (k < IN) ? eWih[(d * GG + j) * IN + k]
                           : eWhh[(d * GG + j) * HH + (k - IN)];
        uint_t hi, lo; bfsplit(v, hi, lo);
        g_webh[idx] = (ush)hi; g_webl[idx] = (ush)lo;
        return;
    }
    idx -= N_WT;
    if (idx < N_WT) {                 // dec
        int d   = idx / (4 * 256 * KTOT);
        int sub = idx % (4 * 256 * KTOT);
        int g   = sub / (256 * KTOT);
        int n2  = (sub / KTOT) % 256;
        int k   = sub % KTOT;
        int j   = g * HH + n2;
        float v = (k < IN) ? dWih[(d * GG + j) * IN + k]
                           : dWhh[(d * GG + j) * HH + (k - IN)];
        uint_t hi, lo; bfsplit(v, hi, lo);
        g_wdbh[idx] = (ush)hi; g_wdbl[idx] = (ush)lo;
        return;
    }
    idx -= N_WT;
    if (idx < N_LW) {                 // linW [o][k] (already row-major (64,512))
        float v = linW[idx];
        uint_t hi, lo; bfsplit(v, hi, lo);
        g_lwbh[idx] = (ush)hi; g_lwbl[idx] = (ush)lo;
        return;
    }
    idx -= N_LW;
    if (idx < 2 * GG) { g_bs_enc[idx] = ebih[idx] + ebhh[idx]; return; }
    idx -= 2 * GG;
    if (idx < 2 * GG) { g_bs_dec[idx] = dbih[idx] + dbhh[idx]; return; }
    idx -= 2 * GG;
    if (idx < IN) { g_linb[idx] = linb[idx]; return; }
    idx -= IN;
    if (idx < 16) { g_xflag[idx] = 0; return; }
}

__device__ __forceinline__ float sigm(float v) { return 1.0f / (1.0f + expf(-v)); }

__device__ __forceinline__ float agent_ldf(const float* p) {
    return __hip_atomic_load(p, __ATOMIC_RELAXED, __HIP_MEMORY_SCOPE_AGENT);
}
__device__ __forceinline__ void agent_stf(float* p, float v) {
    __hip_atomic_store(p, v, __ATOMIC_RELAXED, __HIP_MEMORY_SCOPE_AGENT);
}
__device__ __forceinline__ int agent_ldi(const int* p) {
    return __hip_atomic_load(p, __ATOMIC_RELAXED, __HIP_MEMORY_SCOPE_AGENT);
}
__device__ __forceinline__ void agent_sti(int* p, int v) {
    __hip_atomic_store(p, v, __ATOMIC_RELAXED, __HIP_MEMORY_SCOPE_AGENT);
}

// 16 blocks x 1024 threads (16 waves). Block = (dir, btile): owns 16 batch
// rows for ONE direction, with the ENTIRE per-dir weight matrix [1024n x 320k]
// (bf16 hi+lo) resident in registers: wave w holds n-cols [w*16, w*16+16) of
// all 4 gates (4 gates x 10 kc x hi/lo = 80 s8v = 320 VGPR/lane).
// Per step (block-local, zero inter-block traffic):
//   S: stage x/y (k<64) into sA[p] frag layout (h-part written by prev C)
//   B: 120 MFMAs/wave (3-term hi/lo split, baseline-exact numerics)
//   C: activation (expf/tanhf, baseline-exact), write h -> sA[p^1] h-part
// Cross-block traffic ONLY at the 24 decoder heads (cross-dir concat):
// baseline-proven flag rendezvous (data agent-stores -> s_waitcnt(0) ->
// barrier -> monotonic flag; poll -> barrier -> data loads) on once-written
// t-indexed buffers (ABA-free by construction).
__global__ __launch_bounds__(1024)
void lstm_main(const float* __restrict__ x, float* __restrict__ out)
{
    __shared__ __align__(16) ush   sAh[2][10 * 64 * 8];   // 2 x 10 KB, A hi
    __shared__ __align__(16) ush   sAl[2][10 * 64 * 8];   // 2 x 10 KB, A lo
    __shared__ __align__(16) float hbuf[16][256];         // 16 KB own-dir h
    __shared__ __align__(16) float pbuf[16][256];         // 16 KB peer-dir h
    __shared__ __align__(16) ush   sHh[16 * 512];         // 16 KB feat hi (head)
    __shared__ __align__(16) ush   sHl[16 * 512];         // 16 KB feat lo

    const int tid   = threadIdx.x;
    const int blk   = blockIdx.x;
    const int dir   = blk & 1;
    const int btile = blk >> 1;
    const int b0    = btile * 16;
    const int wave  = tid >> 6;
    const int lane  = tid & 63;
    const int quad  = lane >> 4;
    const int n16   = lane & 15;
    const int wn0   = wave * 16;
    const int srow  = tid >> 6;      // staging row (0..15)
    const int sk    = tid & 63;      // staging k   (0..63)

    s8v   rbh[4][10], rbl[4][10];    // register-resident B (this wave's slice)
    float bw[4];

    auto load_w = [&](const ush* wh, const ush* wl, const float* bsrc) {
        #pragma unroll
        for (int g = 0; g < 4; ++g) {
            #pragma unroll
            for (int kc = 0; kc < 10; ++kc) {
                int src = ((dir * 4 + g) * 256 + wn0 + n16) * KTOT + kc * 32 + quad * 8;
                rbh[g][kc] = *(const s8v*)(wh + src);
                rbl[g][kc] = *(const s8v*)(wl + src);
            }
            bw[g] = bsrc[dir * GG + g * 256 + wn0 + n16];
        }
    };

    float cst[4] = {0.0f, 0.0f, 0.0f, 0.0f};
    int   p = 0;
    float stage_v;

    // nk: next-input kind for prefetch. 0 = x at time nidx; 1 = yhist[nidx];
    // 2 = none (head will set stage_v). wh_flag: also write h to hbuf (f32).
    auto step = [&](int nk, int nidx, int wh_flag) {
        // ---- S: stage x/y part (k<64) of sA[p] ----
        {
            uint_t hi, lo; bfsplit(stage_v, hi, lo);
            int spos = ((sk >> 5) * 64 + ((sk & 31) >> 3) * 16 + srow) * 8 + (sk & 7);
            sAh[p][spos] = (ush)hi;
            sAl[p][spos] = (ush)lo;
        }
        __syncthreads();
        // ---- prefetch next step's input (latency hidden behind B+C) ----
        float pf = 0.0f;
        if (nk == 0)
            pf = x[((b0 + srow) * SEQL + nidx) * IN + sk];
        else if (nk == 1)
            pf = g_yhist[((dir * 8 + btile) * PREDN + nidx) * 1024 + tid];
        // ---- B: MFMA, 4 gates x 10 kc x 3-term hi/lo split ----
        f4v a0 = {bw[0], bw[0], bw[0], bw[0]};
        f4v a1 = {bw[1], bw[1], bw[1], bw[1]};
        f4v a2 = {bw[2], bw[2], bw[2], bw[2]};
        f4v a3 = {bw[3], bw[3], bw[3], bw[3]};
        const s8v* pAh = (const s8v*)&sAh[p][0];
        const s8v* pAl = (const s8v*)&sAl[p][0];
        #pragma unroll
        for (int kc = 0; kc < 10; ++kc) {
            s8v ah = pAh[kc * 64 + lane];
            s8v al = pAl[kc * 64 + lane];
            a0 = __builtin_amdgcn_mfma_f32_16x16x32_bf16(ah, rbh[0][kc], a0, 0, 0, 0);
            a0 = __builtin_amdgcn_mfma_f32_16x16x32_bf16(ah, rbl[0][kc], a0, 0, 0, 0);
            a0 = __builtin_amdgcn_mfma_f32_16x16x32_bf16(al, rbh[0][kc], a0, 0, 0, 0);
            a1 = __builtin_amdgcn_mfma_f32_16x16x32_bf16(ah, rbh[1][kc], a1, 0, 0, 0);
            a1 = __builtin_amdgcn_mfma_f32_16x16x32_bf16(ah, rbl[1][kc], a1, 0, 0, 0);
            a1 = __builtin_amdgcn_mfma_f32_16x16x32_bf16(al, rbh[1][kc], a1, 0, 0, 0);
            a2 = __builtin_amdgcn_mfma_f32_16x16x32_bf16(ah, rbh[2][kc], a2, 0, 0, 0);
            a2 = __builtin_amdgcn_mfma_f32_16x16x32_bf16(ah, rbl[2][kc], a2, 0, 0, 0);
            a2 = __builtin_amdgcn_mfma_f32_16x16x32_bf16(al, rbh[2][kc], a2, 0, 0, 0);
            a3 = __builtin_amdgcn_mfma_f32_16x16x32_bf16(ah, rbh[3][kc], a3, 0, 0, 0);
            a3 = __builtin_amdgcn_mfma_f32_16x16x32_bf16(ah, rbl[3][kc], a3, 0, 0, 0);
            a3 = __builtin_amdgcn_mfma_f32_16x16x32_bf16(al, rbh[3][kc], a3, 0, 0, 0);
        }
        // ---- C: activation + write h into sA[p^1] h-part ----
        {
            int kcol  = 64 + wn0 + n16;       // this lane's h column as A-k
            int cbase = ((kcol >> 5) * 64 + ((kcol & 31) >> 3) * 16 + quad * 4) * 8
                        + (kcol & 7);
            #pragma unroll
            for (int r2 = 0; r2 < 4; ++r2) {
                float gi = a0[r2], gf = a1[r2], gg2 = a2[r2], go = a3[r2];
                cst[r2] = sigm(gf) * cst[r2] + sigm(gi) * tanhf(gg2);
                float hn = sigm(go) * tanhf(cst[r2]);
                uint_t hi, lo; bfsplit(hn, hi, lo);
                sAh[p ^ 1][cbase + r2 * 8] = (ush)hi;
                sAl[p ^ 1][cbase + r2 * 8] = (ush)lo;
                if (wh_flag) hbuf[quad * 4 + r2][wn0 + n16] = hn;
            }
        }
        __syncthreads();
        stage_v = pf;
        p ^= 1;
    };

    // ---- head: rendezvous with peer dir, y = concat(hF,hB) @ linW^T + b ----
    auto head = [&](int t) {
        // publish own final h (once-written, t-indexed)
        {
            float4 hv = *(const float4*)&hbuf[tid >> 6][(tid & 63) * 4];
            float* dst = &g_hx[((t * 2 + dir) * 8 + btile) * 4096 + tid * 4];
            agent_stf(dst + 0, hv.x); agent_stf(dst + 1, hv.y);
            agent_stf(dst + 2, hv.z); agent_stf(dst + 3, hv.w);
        }
        __builtin_amdgcn_s_waitcnt(0);   // this wave's stores reached IC
        __syncthreads();                 // all waves' stores done
        if (tid == 0) {
            agent_sti(&g_xflag[dir * 8 + btile], t + 1);
            while (agent_ldi(&g_xflag[(dir ^ 1) * 8 + btile]) < t + 1)
                __builtin_amdgcn_s_sleep(4);
        }
        __syncthreads();
        // load peer h
        {
            const float* srcp = &g_hx[((t * 2 + (dir ^ 1)) * 8 + btile) * 4096 + tid * 4];
            float v0 = agent_ldf(srcp + 0), v1 = agent_ldf(srcp + 1);
            float v2 = agent_ldf(srcp + 2), v3 = agent_ldf(srcp + 3);
            float* d = &pbuf[tid >> 6][(tid & 63) * 4];
            d[0] = v0; d[1] = v1; d[2] = v2; d[3] = v3;
        }
        __syncthreads();
        // stage feat = [hF, hB] into A-frag layout (16 kc)
        {
            const float* HFb = dir ? &pbuf[0][0] : &hbuf[0][0];
            const float* HBb = dir ? &hbuf[0][0] : &pbuf[0][0];
            int r = tid >> 6;
            #pragma unroll
            for (int q = 0; q < 8; ++q) {
                int kk = ((tid & 63) << 3) + q;
                float fv = (kk < 256) ? HFb[r * 256 + kk] : HBb[r * 256 + kk - 256];
                uint_t hi, lo; bfsplit(fv, hi, lo);
                int posn = ((kk >> 5) * 64 + ((kk & 31) >> 3) * 16 + r) * 8 + (kk & 7);
                sHh[posn] = (ush)hi; sHl[posn] = (ush)lo;
            }
        }
        __syncthreads();
        // y[16b x 64o] via MFMA on waves 0..3
        if (wave < 4) {
            float bias = g_linb[wn0 + n16];
            f4v acc = {bias, bias, bias, bias};
            const s8v* pHh = (const s8v*)sHh;
            const s8v* pHl = (const s8v*)sHl;
            #pragma unroll
            for (int kc = 0; kc < 16; ++kc) {
                s8v fh = pHh[kc * 64 + lane];
                s8v fl = pHl[kc * 64 + lane];
                int wsrc = (wn0 + n16) * 512 + kc * 32 + quad * 8;
                s8v wwh = *(const s8v*)(g_lwbh + wsrc);
                s8v wwl = *(const s8v*)(g_lwbl + wsrc);
                acc = __builtin_amdgcn_mfma_f32_16x16x32_bf16(fh, wwh, acc, 0, 0, 0);
                acc = __builtin_amdgcn_mfma_f32_16x16x32_bf16(fh, wwl, acc, 0, 0, 0);
                acc = __builtin_amdgcn_mfma_f32_16x16x32_bf16(fl, wwh, acc, 0, 0, 0);
            }
            #pragma unroll
            for (int r2 = 0; r2 < 4; ++r2) {
                float y = acc[r2];
                g_yhist[((dir * 8 + btile) * PREDN + t) * 1024
                        + (quad * 4 + r2) * 64 + wn0 + n16] = y;
                if (dir == 0)
                    out[(b0 + quad * 4 + r2) * (PREDN * IN) + t * IN + wn0 + n16] = y;
            }
        }
        __syncthreads();   // yhist globally visible within block (vmcnt drain)
        if (t < PREDN - 1) {
            int e0 = dir ? t : 0;   // next iteration's sub-step-0 input
            stage_v = g_yhist[((dir * 8 + btile) * PREDN + e0) * 1024 + tid];
        }
    };

    // ---------------- encoder: 336 block-local steps ----------------
    load_w(g_webh, g_webl, g_bs_enc);
    for (int i = tid; i < 4096; i += 1024) {      // zero h-part of sA[0]
        sAh[0][1024 + i] = 0; sAl[0][1024 + i] = 0;
    }
    stage_v = x[((b0 + srow) * SEQL + (dir ? SEQL - 1 : 0)) * IN + sk];
    __syncthreads();

    for (int t = 0; t < SEQL; ++t) {
        // prefetch: next enc step's x, or (at t=335) the decoder-t0 input
        int nidx = (t < SEQL - 1) ? (dir ? SEQL - 2 - t : t + 1) : (SEQL - 1);
        step(0, nidx, 0);
    }

    load_w(g_wdbh, g_wdbl, g_bs_dec);             // registers only; no sync

    // ---------------- decoder: 24 iterations ----------------
    for (int t = 0; t < PREDN; ++t) {
        int L = t ? t : 1;
        for (int s = 0; s < L; ++s) {
            int last = (s == L - 1);
            int nk   = last ? 2 : 1;
            int nidx = last ? 0 : (dir ? L - 2 - s : s + 1);
            step(nk, nidx, last);
        }
        head(t);
    }
}

extern "C" void kernel_launch(void* const* d_in, const int* in_sizes, int n_in,
                              void* d_out, int out_size, void* d_ws, size_t ws_size,
                              hipStream_t stream)
{
    (void)in_sizes; (void)n_in; (void)out_size; (void)d_ws; (void)ws_size;
    const float* x    = (const float*)d_in[0];
    const float* eWih = (const float*)d_in[1];
    const float* eWhh = (const float*)d_in[2];
    const float* ebih = (const float*)d_in[3];
    const float* ebhh = (const float*)d_in[4];
    const float* dWih = (const float*)d_in[5];
    const float* dWhh = (const float*)d_in[6];
    const float* dbih = (const float*)d_in[7];
    const float* dbhh = (const float*)d_in[8];
    const float* linW = (const float*)d_in[9];
    const float* linb = (const float*)d_in[10];
    float* out = (float*)d_out;

    int prep_blocks = (N_PREP + 255) / 256;
    hipLaunchKernelGGL(prep_kernel, dim3(prep_blocks), dim3(256), 0, stream,
                       eWih, eWhh, ebih, ebhh, dWih, dWhh, dbih, dbhh, linW, linb);

    void* args[] = { (void*)&x, (void*)&out };
    (void)hipLaunchCooperativeKernel((void*)lstm_main, dim3(NBLK), dim3(1024), args, 0, stream);
}

// Round 6
// 5100.750 us; speedup vs baseline: 3.7102x; 3.7102x over previous
//
#include <hip/hip_runtime.h>

#define BB    128
#define SEQL  336
#define PREDN 24
#define IN    64
#define HH    256
#define GG    1024          // 4*H
#define KTOT  320           // IN + H
#define NBLK  64            // 2 dir x 4 q x 8 btile; 256 thr (4 waves)

typedef unsigned int   uint_t;
typedef unsigned short ush;
using s8v = __attribute__((ext_vector_type(8))) short;   // 8 bf16 (4 VGPRs)
using f4v = __attribute__((ext_vector_type(4))) float;   // MFMA acc

// ---- static device scratch (.bss; re-initialized by prep every call) ----
__device__ ush   g_webh[2 * 4 * 256 * KTOT];  // enc W bf16-hi [dir][gate][n][k]
__device__ ush   g_webl[2 * 4 * 256 * KTOT];  // enc W bf16-lo
__device__ ush   g_wdbh[2 * 4 * 256 * KTOT];  // dec W bf16-hi
__device__ ush   g_wdbl[2 * 4 * 256 * KTOT];  // dec W bf16-lo
__device__ float g_linwt[2 * HH * IN];        // [k2][o]
__device__ float g_bs_enc[2 * GG];
__device__ float g_bs_dec[2 * GG];
__device__ float g_linb[IN];
__device__ float g_h[2][2 * BB * HH];         // ping-pong [p][dir][b][n]  (f32)
__device__ float g_ys[PREDN * BB * IN];       // decoder feedback (f32, t-indexed)
__device__ float g_hfin[PREDN * 8 * 8192];    // head h: [t][btile][(dir*HH+col)*16+row]
__device__ int   g_flag[NBLK * 16];           // per-block event counter, 64 B apart

#define N_WT   (2 * 4 * 256 * KTOT)           // 655360
#define N_PREP (2 * N_WT + 2 * HH * IN + 4 * GG + IN + 2 * 2 * BB * HH + PREDN * BB * IN + NBLK * 16)

__device__ __forceinline__ void bfsplit(float v, uint_t& hi, uint_t& lo) {
    uint_t u = __float_as_uint(v);
    uint_t h = (u + 0x7FFFu + ((u >> 16) & 1u)) >> 16;          // RTN-even bf16
    float  r = v - __uint_as_float(h << 16);
    uint_t u2 = __float_as_uint(r);
    uint_t l = (u2 + 0x7FFFu + ((u2 >> 16) & 1u)) >> 16;
    hi = h; lo = l;
}

// Weights -> bf16 hi/lo [dir][gate][n][k]; combine biases; zero h/ys/flags.
// (R0-proven prep, verbatim structure.)
__global__ void prep_kernel(const float* __restrict__ eWih,
                            const float* __restrict__ eWhh,
                            const float* __restrict__ ebih,
                            const float* __restrict__ ebhh,
                            const float* __restrict__ dWih,
                            const float* __restrict__ dWhh,
                            const float* __restrict__ dbih,
                            const float* __restrict__ dbhh,
                            const float* __restrict__ linW,
                            const float* __restrict__ linb)
{
    int idx = blockIdx.x * 256 + threadIdx.x;
    if (idx >= N_PREP) return;

    if (idx < N_WT) {                 // enc
        int d   = idx / (4 * 256 * KTOT);
        int sub = idx % (4 * 256 * KTOT);
        int g   = sub / (256 * KTOT);
        int n2  = (sub / KTOT) % 256;
        int k   = sub % KTOT;
        int j   = g * HH + n2;
        float v = (k < IN) ? eWih[(d * GG + j) * IN + k]
                           : eWhh[(d * GG + j) * HH + (k - IN)];
        uint_t hi, lo; bfsplit(v, hi, lo);
        g_webh[idx] = (ush)hi; g_webl[idx] = (ush)lo;
        return;
    }
    idx -= N_WT;
    if (idx < N_WT) {                 // dec
        int d   = idx / (4 * 256 * KTOT);
        int sub = idx % (4 * 256 * KTOT);
        int g   = sub / (256 * KTOT);
        int n2  = (sub / KTOT) % 256;
        int k   = sub % KTOT;
        int j   = g * HH + n2;
        float v = (k < IN) ? dWih[(d * GG + j) * IN + k]
                           : dWhh[(d * GG + j) * HH + (k - IN)];
        uint_t hi, lo; bfsplit(v, hi, lo);
        g_wdbh[idx] = (ush)hi; g_wdbl[idx] = (ush)lo;
        return;
    }
    idx -= N_WT;
    if (idx < 2 * HH * IN) {          // linWT[k2][o]
        int k = idx / IN, o = idx % IN;
        g_linwt[idx] = linW[o * (2 * HH) + k];
        return;
    }
    idx -= 2 * HH * IN;
    if (idx < 2 * GG) { g_bs_enc[idx] = ebih[idx] + ebhh[idx]; return; }
    idx -= 2 * GG;
    if (idx < 2 * GG) { g_bs_dec[idx] = dbih[idx] + dbhh[idx]; return; }
    idx -= 2 * GG;
    if (idx < IN) { g_linb[idx] = linb[idx]; return; }
    idx -= IN;
    if (idx < 2 * 2 * BB * HH) { ((float*)g_h)[idx] = 0.0f; return; }
    idx -= 2 * 2 * BB * HH;
    if (idx < PREDN * BB * IN) { g_ys[idx] = 0.0f; return; }
    idx -= PREDN * BB * IN;
    if (idx < NBLK * 16) { g_flag[idx] = 0; return; }
}

__device__ __forceinline__ float sigm(float v) { return 1.0f / (1.0f + expf(-v)); }

__device__ __forceinline__ float agent_ld(const float* p) {
    return __hip_atomic_load(p, __ATOMIC_RELAXED, __HIP_MEMORY_SCOPE_AGENT);
}
__device__ __forceinline__ void agent_st(float* p, float v) {
    __hip_atomic_store(p, v, __ATOMIC_RELAXED, __HIP_MEMORY_SCOPE_AGENT);
}
__device__ __forceinline__ int agent_ldi(const int* p) {
    return __hip_atomic_load(p, __ATOMIC_RELAXED, __HIP_MEMORY_SCOPE_AGENT);
}
__device__ __forceinline__ void agent_sti(int* p, int v) {
    __hip_atomic_store(p, v, __ATOMIC_RELAXED, __HIP_MEMORY_SCOPE_AGENT);
}

// PLAIN (non-cooperative) launch: no grid-sync API is used anywhere; 64 blocks
// on a 256-CU chip are trivially co-resident, so the R0-proven flag protocol
// is valid. blk: dir = blk>>5, q = (blk>>3)&3, btile = blk&7  (group members
// share blk%8 -> same XCD for cheap group-local coherence traffic).
//
// Group (dir,btile) = 4 blocks computes one dir's full step for 16 batch
// rows. Wave w of block q owns n-cols colG = q*64 + w*16 + (lane&15) for ALL
// 4 gates: B-frags = 4 gates x 10 kc x hi/lo = 320 VGPR, register-resident
// (R4's design at a thread count where it fits: 256 thr = 1 wave/SIMD = 512
// VGPR budget). Per step: stage A in LDS (R0's exact staging code: x f32
// loads + h agent f32 loads, consumer-side bfsplit, frag-order writes) ->
// barrier -> 120 MFMA/wave -> D-frag activation (R4-proven mapping: row =
// quad*4+r2, col = colG) -> h agent f32 stores -> R0's sync_g. Heads (24x):
// per-btile 8-block rendezvous (sync_g(8)), one block computes y = feat @
// linW^T + b from t-indexed g_hfin, publishes g_ys[t], everyone sync_g(8).
__global__ __launch_bounds__(256, 1)
void lstm_main(const float* __restrict__ x, float* __restrict__ out)
{
    __shared__ __align__(16) ush  sAh[10 * 64 * 8];       // 10 KB  A hi (frag order)
    __shared__ __align__(16) ush  sAl[10 * 64 * 8];       // 10 KB  A lo
    __shared__ float umf[16][513];                        // 33 KB  head feat staging

    const int tid   = threadIdx.x;
    const int blk   = blockIdx.x;
    const int dir   = blk >> 5;
    const int q     = (blk >> 3) & 3;
    const int btile = blk & 7;
    const int b0    = btile * 16;
    const int wave  = tid >> 6;
    const int lane  = tid & 63;
    const int quad  = lane >> 4;
    const int n16   = lane & 15;
    const int colG  = q * 64 + wave * 16 + n16;   // this lane's n-col (per gate)

    int* myflag = &g_flag[blk * 16];
    int  ev = 0;

    auto sync_g = [&](int nwait) {
        ++ev;
        __atomic_signal_fence(__ATOMIC_SEQ_CST);
        __builtin_amdgcn_s_waitcnt(0);     // this wave's stores reached coherence pt
        __atomic_signal_fence(__ATOMIC_SEQ_CST);
        __syncthreads();
        if (tid == 0) agent_sti(myflag, ev);
        if (tid < nwait) {
            int d = (nwait == 8) ? (tid >> 2) : dir;
            int m = (nwait == 8) ? (tid & 3) : tid;
            int* f = &g_flag[(d * 32 + m * 8 + btile) * 16];
            while (agent_ldi(f) < ev) __builtin_amdgcn_s_sleep(1);
        }
        __atomic_signal_fence(__ATOMIC_SEQ_CST);
        __syncthreads();
    };

    s8v   rbh[4][10], rbl[4][10];     // register-resident B (this wave's slice)
    float bw[4];
    auto load_w = [&](const ush* wh, const ush* wl, const float* bsrc) {
        #pragma unroll
        for (int g4 = 0; g4 < 4; ++g4) {
            #pragma unroll
            for (int kc = 0; kc < 10; ++kc) {
                int src = ((dir * 4 + g4) * 256 + colG) * KTOT + kc * 32 + quad * 8;
                rbh[g4][kc] = *(const s8v*)(wh + src);
                rbl[g4][kc] = *(const s8v*)(wl + src);
            }
            bw[g4] = bsrc[dir * GG + g4 * 256 + colG];
        }
    };

    float cst[4] = {0.0f, 0.0f, 0.0f, 0.0f};
    int   p = 0;

    // mode 0: encoder step tval; 1: decoder t=0 (x last step); 2: ys sub-step.
    // fin_t >= 0: last sub-step of decoder iteration fin_t -> publish g_hfin.
    auto step = [&](int mode, int tval, int L, int fin_t) {
        float* hsrc = g_h[p];
        // ---- stage x/ys into A frags (cols 0..63)  [R0 verbatim] ----
        if (mode <= 1) {
            int xb = tid >> 4, xj = tid & 15;
            int te = (mode == 0) ? (dir ? (SEQL - 1 - tval) : tval) : (SEQL - 1);
            float4 xv = ((const float4*)(x + ((b0 + xb) * SEQL + te) * IN))[xj];
            uint_t h0,l0,h1,l1,h2,l2,h3,l3;
            bfsplit(xv.x,h0,l0); bfsplit(xv.y,h1,l1); bfsplit(xv.z,h2,l2); bfsplit(xv.w,h3,l3);
            int k = 4 * xj;
            int base = (((k >> 5) * 64 + ((k & 31) >> 3) * 16 + xb) * 8) + (k & 7);
            *(uint_t*)&sAh[base]     = h0 | (h1 << 16);
            *(uint_t*)&sAh[base + 2] = h2 | (h3 << 16);
            *(uint_t*)&sAl[base]     = l0 | (l1 << 16);
            *(uint_t*)&sAl[base + 2] = l2 | (l3 << 16);
        } else {
            int e = dir ? (L - 1 - tval) : tval;
            float yv[4];
            #pragma unroll
            for (int jj = 0; jj < 4; ++jj) {
                int i = tid + jj * 256;
                yv[jj] = agent_ld(g_ys + (e * BB + b0 + (i >> 6)) * IN + (i & 63));
            }
            #pragma unroll
            for (int jj = 0; jj < 4; ++jj) {
                int i = tid + jj * 256;
                int yb = i >> 6, k = i & 63;
                uint_t hi, lo; bfsplit(yv[jj], hi, lo);
                int base = (((k >> 5) * 64 + ((k & 31) >> 3) * 16 + yb) * 8) + (k & 7);
                sAh[base] = (ush)hi; sAl[base] = (ush)lo;
            }
        }
        // ---- stage h into A frags (cols 64..319)  [R0 verbatim] ----
        {
            int hb = tid & 15, cblk = tid >> 4;
            const float* hp = hsrc + (dir * BB + b0 + hb) * HH + cblk * 16;
            float rh[16];
            #pragma unroll
            for (int m = 0; m < 16; ++m) rh[m] = agent_ld(hp + m);
            #pragma unroll
            for (int m = 0; m < 16; m += 2) {
                int k = IN + cblk * 16 + m;
                uint_t h0,l0,h1,l1;
                bfsplit(rh[m], h0, l0); bfsplit(rh[m+1], h1, l1);
                int base = (((k >> 5) * 64 + ((k & 31) >> 3) * 16 + hb) * 8) + (k & 7);
                *(uint_t*)&sAh[base] = h0 | (h1 << 16);
                *(uint_t*)&sAl[base] = l0 | (l1 << 16);
            }
        }
        __syncthreads();

        // ---- MFMA: 4 gates x 10 kc x 3-term hi/lo split ----
        f4v a0 = {bw[0], bw[0], bw[0], bw[0]};
        f4v a1 = {bw[1], bw[1], bw[1], bw[1]};
        f4v a2 = {bw[2], bw[2], bw[2], bw[2]};
        f4v a3 = {bw[3], bw[3], bw[3], bw[3]};
        const s8v* pAh = (const s8v*)sAh;
        const s8v* pAl = (const s8v*)sAl;
        #pragma unroll
        for (int kc = 0; kc < 10; ++kc) {
            s8v ah = pAh[kc * 64 + lane];
            s8v al = pAl[kc * 64 + lane];
            a0 = __builtin_amdgcn_mfma_f32_16x16x32_bf16(ah, rbh[0][kc], a0, 0, 0, 0);
            a0 = __builtin_amdgcn_mfma_f32_16x16x32_bf16(ah, rbl[0][kc], a0, 0, 0, 0);
            a0 = __builtin_amdgcn_mfma_f32_16x16x32_bf16(al, rbh[0][kc], a0, 0, 0, 0);
            a1 = __builtin_amdgcn_mfma_f32_16x16x32_bf16(ah, rbh[1][kc], a1, 0, 0, 0);
            a1 = __builtin_amdgcn_mfma_f32_16x16x32_bf16(ah, rbl[1][kc], a1, 0, 0, 0);
            a1 = __builtin_amdgcn_mfma_f32_16x16x32_bf16(al, rbh[1][kc], a1, 0, 0, 0);
            a2 = __builtin_amdgcn_mfma_f32_16x16x32_bf16(ah, rbh[2][kc], a2, 0, 0, 0);
            a2 = __builtin_amdgcn_mfma_f32_16x16x32_bf16(ah, rbl[2][kc], a2, 0, 0, 0);
            a2 = __builtin_amdgcn_mfma_f32_16x16x32_bf16(al, rbh[2][kc], a2, 0, 0, 0);
            a3 = __builtin_amdgcn_mfma_f32_16x16x32_bf16(ah, rbh[3][kc], a3, 0, 0, 0);
            a3 = __builtin_amdgcn_mfma_f32_16x16x32_bf16(ah, rbl[3][kc], a3, 0, 0, 0);
            a3 = __builtin_amdgcn_mfma_f32_16x16x32_bf16(al, rbh[3][kc], a3, 0, 0, 0);
        }

        // ---- D-frag activation (R4-proven mapping) + f32 h publish ----
        {
            float* hdst = g_h[p ^ 1];
            #pragma unroll
            for (int r2 = 0; r2 < 4; ++r2) {
                float gi = a0[r2], gf = a1[r2], gg2 = a2[r2], go = a3[r2];
                cst[r2] = sigm(gf) * cst[r2] + sigm(gi) * tanhf(gg2);
                float hn = sigm(go) * tanhf(cst[r2]);
                int row = quad * 4 + r2;
                agent_st(&hdst[(dir * BB + b0 + row) * HH + colG], hn);
                if (fin_t >= 0)
                    agent_st(&g_hfin[(fin_t * 8 + btile) * 8192
                                     + (dir * HH + colG) * 16 + row], hn);
            }
        }
        p ^= 1;
        sync_g((fin_t >= 0) ? 8 : 4);
    };

    // ---- head (block blk==btile, i.e. dir0/q0): y = concat(hF,hB)@linW^T+b ----
    auto head = [&](int t) {
        if (blk < 8) {
            #pragma unroll
            for (int jj = 0; jj < 32; ++jj) {
                int gi = tid + jj * 256;          // k2*16 + row
                umf[gi & 15][gi >> 4] =
                    agent_ld(&g_hfin[(t * 8 + btile) * 8192 + gi]);
            }
            __syncthreads();
            int row = tid >> 4, og = tid & 15;
            float acc[4];
            #pragma unroll
            for (int oi = 0; oi < 4; ++oi) acc[oi] = g_linb[og * 4 + oi];
            for (int k2 = 0; k2 < 512; ++k2) {
                float hv = umf[row][k2];
                #pragma unroll
                for (int oi = 0; oi < 4; ++oi)
                    acc[oi] = fmaf(hv, g_linwt[k2 * IN + og * 4 + oi], acc[oi]);
            }
            #pragma unroll
            for (int oi = 0; oi < 4; ++oi) {
                int o = og * 4 + oi;
                out[(b0 + row) * (PREDN * IN) + t * IN + o] = acc[oi];
                agent_st(&g_ys[(t * BB + b0 + row) * IN + o], acc[oi]);
            }
        }
        sync_g(8);    // y visible btile-wide before next iteration's staging
    };

    // ---------------- encoder: 336 group-local steps ----------------
    load_w(g_webh, g_webl, g_bs_enc);
    for (int t = 0; t < SEQL; ++t) step(0, t, 0, -1);

    load_w(g_wdbh, g_wdbl, g_bs_dec);   // registers only; no sync needed

    // ---------------- decoder: 24 iterations ----------------
    for (int t = 0; t < PREDN; ++t) {
        int L = t ? t : 1;
        for (int s = 0; s < L; ++s)
            step((t == 0) ? 1 : 2, s, L, (s == L - 1) ? t : -1);
        head(t);
    }
}

extern "C" void kernel_launch(void* const* d_in, const int* in_sizes, int n_in,
                              void* d_out, int out_size, void* d_ws, size_t ws_size,
                              hipStream_t stream)
{
    (void)in_sizes; (void)n_in; (void)out_size; (void)d_ws; (void)ws_size;
    const float* x    = (const float*)d_in[0];
    const float* eWih = (const float*)d_in[1];
    const float* eWhh = (const float*)d_in[2];
    const float* ebih = (const float*)d_in[3];
    const float* ebhh = (const float*)d_in[4];
    const float* dWih = (const float*)d_in[5];
    const float* dWhh = (const float*)d_in[6];
    const float* dbih = (const float*)d_in[7];
    const float* dbhh = (const float*)d_in[8];
    const float* linW = (const float*)d_in[9];
    const float* linb = (const float*)d_in[10];
    float* out = (float*)d_out;

    int prep_blocks = (N_PREP + 255) / 256;
    hipLaunchKernelGGL(prep_kernel, dim3(prep_blocks), dim3(256), 0, stream,
                       eWih, eWhh, ebih, ebhh, dWih, dWhh, dbih, dbhh, linW, linb);

    // Plain launch: no grid-sync API used; 64 blocks <= 256 CUs co-reside.
    hipLaunchKernelGGL(lstm_main, dim3(NBLK), dim3(256), 0, stream, x, out);
}

// Round 7
// 4707.896 us; speedup vs baseline: 4.0198x; 1.0834x over previous
//
#include <hip/hip_runtime.h>

#define BB    128
#define SEQL  336
#define PREDN 24
#define IN    64
#define HH    256
#define GG    1024          // 4*H
#define KTOT  320           // IN + H
#define NBLK  128           // 2 dir x 8 q x 8 btile; 256 thr (4 waves)

typedef unsigned int   uint_t;
typedef unsigned short ush;
using s8v = __attribute__((ext_vector_type(8))) short;   // 8 bf16 (4 VGPRs)
using f4v = __attribute__((ext_vector_type(4))) float;   // MFMA acc

// ---- static device scratch (.bss; re-initialized by prep every call) ----
__device__ ush   g_webh[2 * 4 * 256 * KTOT];  // enc W bf16-hi [dir][gate][n][k]
__device__ ush   g_webl[2 * 4 * 256 * KTOT];  // enc W bf16-lo
__device__ ush   g_wdbh[2 * 4 * 256 * KTOT];  // dec W bf16-hi
__device__ ush   g_wdbl[2 * 4 * 256 * KTOT];  // dec W bf16-lo
__device__ float g_linwt[2 * HH * IN];        // [k2][o]
__device__ float g_bs_enc[2 * GG];
__device__ float g_bs_dec[2 * GG];
__device__ float g_linb[IN];
__device__ float g_h[2][2 * BB * HH];         // ping-pong [p][dir][b][n]  (f32)
__device__ float g_ys[PREDN * BB * IN];       // decoder feedback (f32, t-indexed)
__device__ float g_hfin[PREDN * 8 * 8192];    // head h: [t][btile][(dir*HH+col)*16+row]
__device__ int   g_flag[NBLK * 16];           // per-block event counter, 64 B apart

#define N_WT   (2 * 4 * 256 * KTOT)           // 655360
#define N_PREP (2 * N_WT + 2 * HH * IN + 4 * GG + IN + 2 * 2 * BB * HH + PREDN * BB * IN + NBLK * 16)

__device__ __forceinline__ void bfsplit(float v, uint_t& hi, uint_t& lo) {
    uint_t u = __float_as_uint(v);
    uint_t h = (u + 0x7FFFu + ((u >> 16) & 1u)) >> 16;          // RTN-even bf16
    float  r = v - __uint_as_float(h << 16);
    uint_t u2 = __float_as_uint(r);
    uint_t l = (u2 + 0x7FFFu + ((u2 >> 16) & 1u)) >> 16;
    hi = h; lo = l;
}

// Weights -> bf16 hi/lo [dir][gate][n][k]; combine biases; zero h/ys/flags.
// (R0-proven prep, verbatim structure.)
__global__ void prep_kernel(const float* __restrict__ eWih,
                            const float* __restrict__ eWhh,
                            const float* __restrict__ ebih,
                            const float* __restrict__ ebhh,
                            const float* __restrict__ dWih,
                            const float* __restrict__ dWhh,
                            const float* __restrict__ dbih,
                            const float* __restrict__ dbhh,
                            const float* __restrict__ linW,
                            const float* __restrict__ linb)
{
    int idx = blockIdx.x * 256 + threadIdx.x;
    if (idx >= N_PREP) return;

    if (idx < N_WT) {                 // enc
        int d   = idx / (4 * 256 * KTOT);
        int sub = idx % (4 * 256 * KTOT);
        int g   = sub / (256 * KTOT);
        int n2  = (sub / KTOT) % 256;
        int k   = sub % KTOT;
        int j   = g * HH + n2;
        float v = (k < IN) ? eWih[(d * GG + j) * IN + k]
                           : eWhh[(d * GG + j) * HH + (k - IN)];
        uint_t hi, lo; bfsplit(v, hi, lo);
        g_webh[idx] = (ush)hi; g_webl[idx] = (ush)lo;
        return;
    }
    idx -= N_WT;
    if (idx < N_WT) {                 // dec
        int d   = idx / (4 * 256 * KTOT);
        int sub = idx % (4 * 256 * KTOT);
        int g   = sub / (256 * KTOT);
        int n2  = (sub / KTOT) % 256;
        int k   = sub % KTOT;
        int j   = g * HH + n2;
        float v = (k < IN) ? dWih[(d * GG + j) * IN + k]
                           : dWhh[(d * GG + j) * HH + (k - IN)];
        uint_t hi, lo; bfsplit(v, hi, lo);
        g_wdbh[idx] = (ush)hi; g_wdbl[idx] = (ush)lo;
        return;
    }
    idx -= N_WT;
    if (idx < 2 * HH * IN) {          // linWT[k2][o]
        int k = idx / IN, o = idx % IN;
        g_linwt[idx] = linW[o * (2 * HH) + k];
        return;
    }
    idx -= 2 * HH * IN;
    if (idx < 2 * GG) { g_bs_enc[idx] = ebih[idx] + ebhh[idx]; return; }
    idx -= 2 * GG;
    if (idx < 2 * GG) { g_bs_dec[idx] = dbih[idx] + dbhh[idx]; return; }
    idx -= 2 * GG;
    if (idx < IN) { g_linb[idx] = linb[idx]; return; }
    idx -= IN;
    if (idx < 2 * 2 * BB * HH) { ((float*)g_h)[idx] = 0.0f; return; }
    idx -= 2 * 2 * BB * HH;
    if (idx < PREDN * BB * IN) { g_ys[idx] = 0.0f; return; }
    idx -= PREDN * BB * IN;
    if (idx < NBLK * 16) { g_flag[idx] = 0; return; }
}

__device__ __forceinline__ float sigm(float v) { return 1.0f / (1.0f + expf(-v)); }

__device__ __forceinline__ float agent_ld(const float* p) {
    return __hip_atomic_load(p, __ATOMIC_RELAXED, __HIP_MEMORY_SCOPE_AGENT);
}
__device__ __forceinline__ void agent_st(float* p, float v) {
    __hip_atomic_store(p, v, __ATOMIC_RELAXED, __HIP_MEMORY_SCOPE_AGENT);
}
__device__ __forceinline__ int agent_ldi(const int* p) {
    return __hip_atomic_load(p, __ATOMIC_RELAXED, __HIP_MEMORY_SCOPE_AGENT);
}
__device__ __forceinline__ void agent_sti(int* p, int v) {
    __hip_atomic_store(p, v, __ATOMIC_RELAXED, __HIP_MEMORY_SCOPE_AGENT);
}

// PLAIN (non-cooperative) launch; 128 blocks <= 256 CUs co-reside trivially.
// blk = dir*64 + q*8 + btile. Group (dir,btile) = 8 q-blocks computes one
// dir's step for 16 batch rows; block q owns n-cols [q*32, q*32+32).
// Wave w = gate w over both 16-col tiles of the block: B-frags = 2 tiles x
// 10 kc x hi/lo = 40 s8v = 160 VGPR -> fits the 256-VGPR budget with NO
// spill (round 6's 320-VGPR ask spilled: VGPR_Count=252, scratch reloads
// serialized the MFMA loop; FETCH_SIZE 113 MB was the smoking gun).
// Cell gates now live in 4 different waves -> R0-proven gbuf LDS exchange
// before activation; each thread finalizes 2 cells (cst[2]).
// Sync: R0-proven sync_g (stores -> s_waitcnt(0) -> barrier -> flag ->
// poll -> barrier). Steps: nwait=8 (own dir group). Fin steps & head:
// nwait=16 (both dirs of this btile). Heads: block blk==btile computes
// y from t-indexed g_hfin, publishes g_ys[t] + out.
__global__ __launch_bounds__(256, 1)
void lstm_main(const float* __restrict__ x, float* __restrict__ out)
{
    __shared__ __align__(16) ush  sAh[10 * 64 * 8];       // 10 KB  A hi (frag order)
    __shared__ __align__(16) ush  sAl[10 * 64 * 8];       // 10 KB  A lo
    __shared__ float gbuf[4][16][33];                     // 8.25 KB gate exchange
    __shared__ float umf[16][513];                        // 33 KB  head feat staging

    const int tid   = threadIdx.x;
    const int blk   = blockIdx.x;
    const int dir   = blk >> 6;
    const int q     = (blk >> 3) & 7;
    const int btile = blk & 7;
    const int b0    = btile * 16;
    const int wave  = tid >> 6;       // = gate index
    const int lane  = tid & 63;
    const int quad  = lane >> 4;
    const int n16   = lane & 15;

    int* myflag = &g_flag[blk * 16];
    int  ev = 0;

    auto sync_g = [&](int nwait) {
        ++ev;
        __atomic_signal_fence(__ATOMIC_SEQ_CST);
        __builtin_amdgcn_s_waitcnt(0);     // this wave's mem ops done (incl. stores)
        __atomic_signal_fence(__ATOMIC_SEQ_CST);
        __syncthreads();
        if (tid == 0) agent_sti(myflag, ev);
        if (tid < nwait) {
            int d = (nwait == 16) ? (tid >> 3) : dir;
            int m = tid & 7;
            int* f = &g_flag[(d * 64 + m * 8 + btile) * 16];
            while (agent_ldi(f) < ev) __builtin_amdgcn_s_sleep(1);
        }
        __atomic_signal_fence(__ATOMIC_SEQ_CST);
        __syncthreads();
    };

    s8v   rbh[2][10], rbl[2][10];     // this wave's B slice: gate=wave, 2 col-tiles
    float bw[2];
    auto load_w = [&](const ush* wh, const ush* wl, const float* bsrc) {
        #pragma unroll
        for (int t2 = 0; t2 < 2; ++t2) {
            int col = q * 32 + t2 * 16 + n16;
            #pragma unroll
            for (int kc = 0; kc < 10; ++kc) {
                int src = ((dir * 4 + wave) * 256 + col) * KTOT + kc * 32 + quad * 8;
                rbh[t2][kc] = *(const s8v*)(wh + src);
                rbl[t2][kc] = *(const s8v*)(wl + src);
            }
            bw[t2] = bsrc[dir * GG + wave * 256 + col];
        }
    };

    float cst[2] = {0.0f, 0.0f};
    int   p = 0;

    // mode 0: encoder step tval; 1: decoder t=0 (x last step); 2: ys sub-step.
    // fin_t >= 0: last sub-step of decoder iteration fin_t -> publish g_hfin.
    auto step = [&](int mode, int tval, int L, int fin_t) {
        float* hsrc = g_h[p];
        // ---- stage x/ys into A frags (cols 0..63)  [R0 verbatim] ----
        if (mode <= 1) {
            int xb = tid >> 4, xj = tid & 15;
            int te = (mode == 0) ? (dir ? (SEQL - 1 - tval) : tval) : (SEQL - 1);
            float4 xv = ((const float4*)(x + ((b0 + xb) * SEQL + te) * IN))[xj];
            uint_t h0,l0,h1,l1,h2,l2,h3,l3;
            bfsplit(xv.x,h0,l0); bfsplit(xv.y,h1,l1); bfsplit(xv.z,h2,l2); bfsplit(xv.w,h3,l3);
            int k = 4 * xj;
            int base = (((k >> 5) * 64 + ((k & 31) >> 3) * 16 + xb) * 8) + (k & 7);
            *(uint_t*)&sAh[base]     = h0 | (h1 << 16);
            *(uint_t*)&sAh[base + 2] = h2 | (h3 << 16);
            *(uint_t*)&sAl[base]     = l0 | (l1 << 16);
            *(uint_t*)&sAl[base + 2] = l2 | (l3 << 16);
        } else {
            int e = dir ? (L - 1 - tval) : tval;
            float yv[4];
            #pragma unroll
            for (int jj = 0; jj < 4; ++jj) {
                int i = tid + jj * 256;
                yv[jj] = agent_ld(g_ys + (e * BB + b0 + (i >> 6)) * IN + (i & 63));
            }
            #pragma unroll
            for (int jj = 0; jj < 4; ++jj) {
                int i = tid + jj * 256;
                int yb = i >> 6, k = i & 63;
                uint_t hi, lo; bfsplit(yv[jj], hi, lo);
                int base = (((k >> 5) * 64 + ((k & 31) >> 3) * 16 + yb) * 8) + (k & 7);
                sAh[base] = (ush)hi; sAl[base] = (ush)lo;
            }
        }
        // ---- stage h into A frags (cols 64..319)  [R0 verbatim] ----
        {
            int hb = tid & 15, cblk = tid >> 4;
            const float* hp = hsrc + (dir * BB + b0 + hb) * HH + cblk * 16;
            float rh[16];
            #pragma unroll
            for (int m = 0; m < 16; ++m) rh[m] = agent_ld(hp + m);
            #pragma unroll
            for (int m = 0; m < 16; m += 2) {
                int k = IN + cblk * 16 + m;
                uint_t h0,l0,h1,l1;
                bfsplit(rh[m], h0, l0); bfsplit(rh[m+1], h1, l1);
                int base = (((k >> 5) * 64 + ((k & 31) >> 3) * 16 + hb) * 8) + (k & 7);
                *(uint_t*)&sAh[base] = h0 | (h1 << 16);
                *(uint_t*)&sAl[base] = l0 | (l1 << 16);
            }
        }
        __syncthreads();

        // ---- MFMA: gate=wave, 2 col-tiles x 10 kc x 3-term hi/lo split ----
        f4v a0 = {bw[0], bw[0], bw[0], bw[0]};
        f4v a1 = {bw[1], bw[1], bw[1], bw[1]};
        const s8v* pAh = (const s8v*)sAh;
        const s8v* pAl = (const s8v*)sAl;
        #pragma unroll
        for (int kc = 0; kc < 10; ++kc) {
            s8v ah = pAh[kc * 64 + lane];
            s8v al = pAl[kc * 64 + lane];
            a0 = __builtin_amdgcn_mfma_f32_16x16x32_bf16(ah, rbh[0][kc], a0, 0, 0, 0);
            a0 = __builtin_amdgcn_mfma_f32_16x16x32_bf16(ah, rbl[0][kc], a0, 0, 0, 0);
            a0 = __builtin_amdgcn_mfma_f32_16x16x32_bf16(al, rbh[0][kc], a0, 0, 0, 0);
            a1 = __builtin_amdgcn_mfma_f32_16x16x32_bf16(ah, rbh[1][kc], a1, 0, 0, 0);
            a1 = __builtin_amdgcn_mfma_f32_16x16x32_bf16(ah, rbl[1][kc], a1, 0, 0, 0);
            a1 = __builtin_amdgcn_mfma_f32_16x16x32_bf16(al, rbh[1][kc], a1, 0, 0, 0);
        }
        // ---- exchange gates via LDS (R0-proven pattern) ----
        #pragma unroll
        for (int r2 = 0; r2 < 4; ++r2) {
            gbuf[wave][quad * 4 + r2][n16]      = a0[r2];
            gbuf[wave][quad * 4 + r2][16 + n16] = a1[r2];
        }
        __syncthreads();

        // ---- activation: thread finalizes 2 cells + f32 h publish ----
        {
            float* hdst = g_h[p ^ 1];
            int row = tid >> 4, cp = (tid & 15) * 2;
            #pragma unroll
            for (int e2 = 0; e2 < 2; ++e2) {
                int col = cp + e2;
                float gi = gbuf[0][row][col];
                float gf = gbuf[1][row][col];
                float gg2 = gbuf[2][row][col];
                float go = gbuf[3][row][col];
                cst[e2] = sigm(gf) * cst[e2] + sigm(gi) * tanhf(gg2);
                float hn = sigm(go) * tanhf(cst[e2]);
                int colG = q * 32 + col;
                agent_st(&hdst[(dir * BB + b0 + row) * HH + colG], hn);
                if (fin_t >= 0)
                    agent_st(&g_hfin[(fin_t * 8 + btile) * 8192
                                     + (dir * HH + colG) * 16 + row], hn);
            }
        }
        p ^= 1;
        sync_g((fin_t >= 0) ? 16 : 8);
    };

    // ---- head (block blk==btile, i.e. dir0/q0): y = concat(hF,hB)@linW^T+b ----
    auto head = [&](int t) {
        if (blk < 8) {
            #pragma unroll
            for (int jj = 0; jj < 32; ++jj) {
                int gi = tid + jj * 256;          // k2*16 + row
                umf[gi & 15][gi >> 4] =
                    agent_ld(&g_hfin[(t * 8 + btile) * 8192 + gi]);
            }
            __syncthreads();
            int row = tid >> 4, og = tid & 15;
            float acc[4];
            #pragma unroll
            for (int oi = 0; oi < 4; ++oi) acc[oi] = g_linb[og * 4 + oi];
            for (int k2 = 0; k2 < 512; ++k2) {
                float hv = umf[row][k2];
                #pragma unroll
                for (int oi = 0; oi < 4; ++oi)
                    acc[oi] = fmaf(hv, g_linwt[k2 * IN + og * 4 + oi], acc[oi]);
            }
            #pragma unroll
            for (int oi = 0; oi < 4; ++oi) {
                int o = og * 4 + oi;
                out[(b0 + row) * (PREDN * IN) + t * IN + o] = acc[oi];
                agent_st(&g_ys[(t * BB + b0 + row) * IN + o], acc[oi]);
            }
        }
        sync_g(16);    // y visible btile-wide before next iteration's staging
    };

    // ---------------- encoder: 336 group-local steps ----------------
    load_w(g_webh, g_webl, g_bs_enc);
    for (int t = 0; t < SEQL; ++t) step(0, t, 0, -1);

    load_w(g_wdbh, g_wdbl, g_bs_dec);   // registers only; no sync needed

    // ---------------- decoder: 24 iterations ----------------
    for (int t = 0; t < PREDN; ++t) {
        int L = t ? t : 1;
        for (int s = 0; s < L; ++s)
            step((t == 0) ? 1 : 2, s, L, (s == L - 1) ? t : -1);
        head(t);
    }
}

extern "C" void kernel_launch(void* const* d_in, const int* in_sizes, int n_in,
                              void* d_out, int out_size, void* d_ws, size_t ws_size,
                              hipStream_t stream)
{
    (void)in_sizes; (void)n_in; (void)out_size; (void)d_ws; (void)ws_size;
    const float* x    = (const float*)d_in[0];
    const float* eWih = (const float*)d_in[1];
    const float* eWhh = (const float*)d_in[2];
    const float* ebih = (const float*)d_in[3];
    const float* ebhh = (const float*)d_in[4];
    const float* dWih = (const float*)d_in[5];
    const float* dWhh = (const float*)d_in[6];
    const float* dbih = (const float*)d_in[7];
    const float* dbhh = (const float*)d_in[8];
    const float* linW = (const float*)d_in[9];
    const float* linb = (const float*)d_in[10];
    float* out = (float*)d_out;

    int prep_blocks = (N_PREP + 255) / 256;
    hipLaunchKernelGGL(prep_kernel, dim3(prep_blocks), dim3(256), 0, stream,
                       eWih, eWhh, ebih, ebhh, dWih, dWhh, dbih, dbhh, linW, linb);

    // Plain launch: no grid-sync API used; 128 blocks <= 256 CUs co-reside.
    hipLaunchKernelGGL(lstm_main, dim3(NBLK), dim3(256), 0, stream, x, out);
}